// Round 5
// baseline (330.882 us; speedup 1.0000x reference)
//
#include <hip/hip_runtime.h>
#include <hip/hip_bf16.h>
#include <math.h>

typedef __bf16 bf16;
typedef __attribute__((ext_vector_type(8))) bf16 bf16x8;
typedef __attribute__((ext_vector_type(4))) bf16 bf16x4;
typedef __attribute__((ext_vector_type(2))) bf16 bf16x2;
typedef __attribute__((ext_vector_type(4))) float f32x4;

#define LOG2E 1.4426950408889634f
#define LOG2_THETA 18.931568569324174f   // log2(500000)

#if __has_builtin(__builtin_amdgcn_exp2f)
#define EXP2F __builtin_amdgcn_exp2f
#else
#define EXP2F exp2f
#endif

// ---- async global->LDS 16B copy (lane-scattered: lds_base + lane*16) ----
__device__ inline void async_cp16(const void* gptr, void* lptr) {
  __builtin_amdgcn_global_load_lds(
      (const __attribute__((address_space(1))) unsigned int*)gptr,
      (__attribute__((address_space(3))) unsigned int*)lptr, 16, 0, 0);
}

// ============================================================
// Fused fp32->bf16 cast of x, wq|wk|wv (contiguous dst), wo.
// ============================================================
__global__ __launch_bounds__(256) void cast_all(
    const float* __restrict__ x,  const float* __restrict__ wq,
    const float* __restrict__ wk, const float* __restrict__ wv,
    const float* __restrict__ wo, bf16* __restrict__ xb,
    bf16* __restrict__ wqkvb, bf16* __restrict__ wob) {
  const int bx = blockIdx.x;
  const size_t gi = ((size_t)bx * 256 + threadIdx.x) * 8;
  const float* src;
  bf16* dst;
  if (bx < 4096)      { src = x  + gi;              dst = xb + gi; }
  else if (bx < 6144) { src = wq + (gi -  8388608); dst = wqkvb + (gi - 8388608); }
  else if (bx < 6656) { src = wk + (gi - 12582912); dst = wqkvb + 4194304 + (gi - 12582912); }
  else if (bx < 7168) { src = wv + (gi - 13631488); dst = wqkvb + 5242880 + (gi - 13631488); }
  else                { src = wo + (gi - 14680064); dst = wob + (gi - 14680064); }
  float4 a = *(const float4*)(src);
  float4 b = *(const float4*)(src + 4);
  bf16x8 o;
  o[0] = (bf16)a.x; o[1] = (bf16)a.y; o[2] = (bf16)a.z; o[3] = (bf16)a.w;
  o[4] = (bf16)b.x; o[5] = (bf16)b.y; o[6] = (bf16)b.z; o[7] = (bf16)b.w;
  *(bf16x8*)dst = o;
}

// ============================================================
// GEMM core: C[M,N] = A[M,K] @ W[N,K]^T, 128x128 tile, BK=64,
// XOR-swizzled LDS, async staging. (unchanged from R4)
// ============================================================
template <typename OUT_T, bool QKV, bool CLIP>
__global__ __launch_bounds__(256) void gemm_bt(
    const bf16* __restrict__ A, const bf16* __restrict__ W,
    const float* __restrict__ b0, const float* __restrict__ b1,
    const float* __restrict__ b2, OUT_T* __restrict__ C,
    int M, int N, int K) {
  __shared__ bf16 As[128 * 64];
  __shared__ bf16 Bs[128 * 64];
  const int m0 = blockIdx.x * 128, n0 = blockIdx.y * 128;
  const int t = threadIdx.x;
  const int w = t >> 6, lane = t & 63, quad = lane >> 4, l15 = lane & 15;
  const int sw = l15 & 7;
  const int wm = (w >> 1) * 64, wn = (w & 1) * 64;

  f32x4 acc[4][4];
#pragma unroll
  for (int i = 0; i < 4; i++)
#pragma unroll
    for (int j = 0; j < 4; j++) acc[i][j] = (f32x4)0.0f;

  int soff[4];
#pragma unroll
  for (int i = 0; i < 4; i++) {
    const int c = w * 256 + i * 64 + lane;
    const int r = c >> 3;
    const int sl = (c & 7) ^ (r & 7);
    soff[i] = r * K + sl * 8;
  }
  const bf16* Abase = A + (size_t)m0 * K;
  const bf16* Wbase = W + (size_t)n0 * K;

  for (int k0 = 0; k0 < K; k0 += 64) {
#pragma unroll
    for (int i = 0; i < 4; i++) {
      const int dst = (w * 256 + i * 64) * 16;
      async_cp16(Abase + k0 + soff[i], (char*)As + dst);
      async_cp16(Wbase + k0 + soff[i], (char*)Bs + dst);
    }
    __syncthreads();

#pragma unroll
    for (int kk = 0; kk < 2; kk++) {
      bf16x8 af[4], bfr[4];
#pragma unroll
      for (int i = 0; i < 4; i++)
        af[i] = *(const bf16x8*)(As + (wm + i * 16 + l15) * 64 +
                                 (((kk * 4 + quad) ^ sw) * 8));
#pragma unroll
      for (int j = 0; j < 4; j++)
        bfr[j] = *(const bf16x8*)(Bs + (wn + j * 16 + l15) * 64 +
                                  (((kk * 4 + quad) ^ sw) * 8));
#pragma unroll
      for (int i = 0; i < 4; i++)
#pragma unroll
        for (int j = 0; j < 4; j++)
          acc[i][j] = __builtin_amdgcn_mfma_f32_16x16x32_bf16(af[i], bfr[j], acc[i][j], 0, 0, 0);
    }
    __syncthreads();
  }

#pragma unroll
  for (int i = 0; i < 4; i++)
#pragma unroll
    for (int j = 0; j < 4; j++) {
      const int col = n0 + wn + j * 16 + l15;
      float bval;
      if (QKV) {
        if (col < 2048) bval = b0[col];
        else if (col < 2560) bval = b1[col - 2048];
        else bval = b2[col - 2560];
      } else {
        bval = b0[col];
      }
#pragma unroll
      for (int r = 0; r < 4; r++) {
        const int row = m0 + wm + i * 16 + quad * 4 + r;
        float v = acc[i][j][r] + bval;
        if (CLIP) v = fminf(fmaxf(v, -8.0f), 8.0f);
        C[(size_t)row * N + col] = (OUT_T)v;
      }
    }
}

// ============================================================
// Fused mid stage (unchanged from R4)
// ============================================================
__global__ __launch_bounds__(256) void fused_mid(
    const bf16* __restrict__ X, const float* __restrict__ qg,
    const float* __restrict__ qb, const float* __restrict__ kg,
    const float* __restrict__ kb, bf16* __restrict__ Qr,
    bf16* __restrict__ Kr, bf16* __restrict__ Vt) {
  __shared__ float smf[2056];
  __shared__ bf16 smt[64][136];
  const int bx = blockIdx.x;
  const int tid = threadIdx.x;
  const int w = tid >> 6, lane = tid & 63;
  float* red = smf + 2048;

  if (bx < 4096) {
    const int row = bx, b = row >> 11, tpos = row & 2047;
    const bf16* x = X + (size_t)row * 3072;
    bf16x8 xi = *(const bf16x8*)(x + tid * 8);
    float v[8];
    float s = 0.0f;
#pragma unroll
    for (int e = 0; e < 8; e++) { v[e] = (float)xi[e]; s += v[e]; }
#pragma unroll
    for (int m = 32; m >= 1; m >>= 1) s += __shfl_xor(s, m, 64);
    if (lane == 0) red[w] = s;
    __syncthreads();
    const float mean = (red[0] + red[1] + red[2] + red[3]) * (1.0f / 2048.0f);
    float vs = 0.0f;
#pragma unroll
    for (int e = 0; e < 8; e++) { float d = v[e] - mean; vs += d * d; }
#pragma unroll
    for (int m = 32; m >= 1; m >>= 1) vs += __shfl_xor(vs, m, 64);
    if (lane == 0) red[4 + w] = vs;
    __syncthreads();
    const float var = (red[4] + red[5] + red[6] + red[7]) * (1.0f / 2048.0f);
    const float rstd = rsqrtf(var + 1e-5f);
#pragma unroll
    for (int e = 0; e < 8; e++) {
      const int c = tid * 8 + e;
      const float y = (v[e] - mean) * rstd * qg[c] + qb[c];
      smf[c] = y; v[e] = y;
    }
    __syncthreads();
    const int c0 = tid * 8;
    const int h = c0 >> 7;
    bf16x8 ov;
#pragma unroll
    for (int e = 0; e < 8; e++) {
      const int c = c0 + e, d = c & 127, i = d & 63;
      const float inv = exp2f((float)i * (-LOG2_THETA / 64.0f));
      float sn, cs;
      sincosf((float)tpos * inv, &sn, &cs);
      const float rot = (d < 64) ? -smf[c + 64] : smf[c - 64];
      ov[e] = (bf16)(v[e] * cs + rot * sn);
    }
    *(bf16x8*)(Qr + ((size_t)(b * 16 + h) * 2048 + tpos) * 128 + (c0 & 127)) = ov;
  } else if (bx < 8192) {
    const int row = bx - 4096, b = row >> 11, tpos = row & 2047;
    const bf16* x = X + (size_t)row * 3072 + 2048;
    bf16x2 xi = *(const bf16x2*)(x + tid * 2);
    float v0 = (float)xi[0], v1 = (float)xi[1];
    float s = v0 + v1;
#pragma unroll
    for (int m = 32; m >= 1; m >>= 1) s += __shfl_xor(s, m, 64);
    if (lane == 0) red[w] = s;
    __syncthreads();
    const float mean = (red[0] + red[1] + red[2] + red[3]) * (1.0f / 512.0f);
    float d0 = v0 - mean, d1 = v1 - mean;
    float vs = d0 * d0 + d1 * d1;
#pragma unroll
    for (int m = 32; m >= 1; m >>= 1) vs += __shfl_xor(vs, m, 64);
    if (lane == 0) red[4 + w] = vs;
    __syncthreads();
    const float var = (red[4] + red[5] + red[6] + red[7]) * (1.0f / 512.0f);
    const float rstd = rsqrtf(var + 1e-5f);
    const int c0 = tid * 2;
    float y0 = d0 * rstd * kg[c0] + kb[c0];
    float y1 = d1 * rstd * kg[c0 + 1] + kb[c0 + 1];
    smf[c0] = y0; smf[c0 + 1] = y1;
    __syncthreads();
    const int kv = c0 >> 7;
    float yy[2] = {y0, y1};
    bf16x2 ov;
#pragma unroll
    for (int e = 0; e < 2; e++) {
      const int c = c0 + e, d = c & 127, i = d & 63;
      const float inv = exp2f((float)i * (-LOG2_THETA / 64.0f));
      float sn, cs;
      sincosf((float)tpos * inv, &sn, &cs);
      const float rot = (d < 64) ? -smf[c + 64] : smf[c - 64];
      ov[e] = (bf16)(yy[e] * cs + rot * sn);
    }
    *(bf16x2*)(Kr + ((size_t)(b * 4 + kv) * 2048 + tpos) * 128 + (c0 & 127)) = ov;
  } else {
    const int idx = bx - 8192;
    const int b = idx >> 7, kv = (idx >> 5) & 3, t0 = (idx & 31) * 64;
#pragma unroll
    for (int i = 0; i < 4; i++) {
      const int c = i * 256 + tid;
      const int r = c >> 4, d8 = (c & 15) * 8;
      *(bf16x8*)&smt[r][d8] =
          *(const bf16x8*)(X + (size_t)(b * 2048 + t0 + r) * 3072 + 2560 + kv * 128 + d8);
    }
    __syncthreads();
#pragma unroll
    for (int i = 0; i < 4; i++) {
      const int c = i * 256 + tid;
      const int d = c >> 3, t8 = (c & 7) * 8;
      bf16x8 o;
#pragma unroll
      for (int j = 0; j < 8; j++) o[j] = smt[t8 + j][d];
      *(bf16x8*)(Vt + (size_t)((b * 4 + kv) * 128 + d) * 2048 + t0 + t8) = o;
    }
  }
}

// ============================================================
// Flash attention v3:
//  - 512 thr, 8 waves = 2 heads x 4 q-strips(16 rows); K/V staged once
//    serves both heads (halves L2 traffic)
//  - grid (16,8,2): block p does q-tiles {31-p, p} -> 33 tiles, balanced
//  - K/V DOUBLE-buffered (64 KB LDS), ONE barrier/tile; staging issued a
//    full iteration ahead of its vmcnt(0) drain
//  - S^T = mfma(Kfrag, Qfrag) (operand swap); P^T -> PV B-operand via 16
//    register shuffles (no P LDS round-trip); O^T = mfma(Vt, P^T)
//  - fixed-max softmax; denominator via all-ones A-operand MFMA
// ============================================================
__global__ __launch_bounds__(512) void flash_attn(
    const bf16* __restrict__ Q, const bf16* __restrict__ Kt,
    const bf16* __restrict__ Vt, bf16* __restrict__ O) {
  __shared__ bf16 Ks[2][64][128];   // [buf][key][d], XOR-swizzled 16B segs
  __shared__ bf16 Vs[2][128][64];   // [buf][d][key], XOR-swizzled 16B segs

  const int p = blockIdx.x;         // 0..15
  const int hp = blockIdx.y;        // 0..7 head-pair
  const int b = blockIdx.z;
  const int kv = hp >> 1;
  const int tid = threadIdx.x;
  const int w = tid >> 6, lane = tid & 63, quad = lane >> 4, l15 = lane & 15;
  const int strip = w & 3, hl = w >> 2;
  const int h = hp * 2 + hl;

  const bf16* Kb = Kt + (size_t)(b * 4 + kv) * 2048 * 128;
  const bf16* Vb = Vt + (size_t)(b * 4 + kv) * 128 * 2048;

  // staging offsets: 1024 16B chunks per matrix; wave w, issue i covers
  // chunks [w*128+i*64, +64). chunk c: K row=c>>4 (phys seg c&15),
  // V row=c>>3 (phys seg c&7); logical seg = phys ^ (row & mask).
  int koff[2], voff[2];
#pragma unroll
  for (int i = 0; i < 2; i++) {
    const int c = w * 128 + i * 64 + lane;
    const int kr = c >> 4, kp = c & 15;
    koff[i] = kr * 128 + ((kp ^ (kr & 15)) * 8);
    const int vd = c >> 3, vp = c & 7;
    voff[i] = vd * 2048 + ((vp ^ (vd & 7)) * 8);
  }

  const float cexp = 0.08838834764831845f * LOG2E;  // (1/sqrt(128))*log2e
  bf16x8 onesA;
#pragma unroll
  for (int i = 0; i < 8; i++) onesA[i] = (bf16)1.0f;

  const int srcA = l15 + ((quad & 1) << 5);   // lane of quad (q&1)*2
  const int srcB = srcA + 16;                 // lane of quad (q&1)*2+1
  const bool hiSel = (quad >> 1) != 0;

#pragma unroll 1
  for (int pass = 0; pass < 2; pass++) {
    const int qb = (pass == 0) ? (31 - p) : p;
    const int q0 = qb * 64;
    const int nkt = qb + 1;
    const int qrow = q0 + strip * 16 + l15;   // this lane's q-row (B n-index)

    const bf16* Qb = Q + ((size_t)(b * 16 + h) * 2048 + qrow) * 128;
    bf16x8 aq[4];
#pragma unroll
    for (int kk = 0; kk < 4; kk++) aq[kk] = *(const bf16x8*)(Qb + kk * 32 + quad * 8);

    f32x4 o[8];
#pragma unroll
    for (int dt = 0; dt < 8; dt++) o[dt] = (f32x4)0.0f;
    f32x4 o8 = (f32x4)0.0f;   // denominator

    __syncthreads();  // previous pass fully done -> buffers reusable
    // prologue: stage tile 0 into buf 0
#pragma unroll
    for (int i = 0; i < 2; i++) {
      const int dst = (w * 128 + i * 64) * 16;
      async_cp16(Kb + koff[i], (char*)Ks + dst);
      async_cp16(Vb + voff[i], (char*)Vs + dst);
    }

#pragma unroll 1
    for (int kt = 0; kt < nkt; kt++) {
      const int k0 = kt * 64;
      const int cur = kt & 1;
      __syncthreads();  // drains staging of buf[cur]; buf[cur^1] free

      if (kt + 1 < nkt) {  // stage next tile into the other buffer
        const size_t kn = (size_t)(k0 + 64);
#pragma unroll
        for (int i = 0; i < 2; i++) {
          const int dst = (w * 128 + i * 64) * 16;
          async_cp16(Kb + kn * 128 + koff[i], (char*)Ks + (cur ^ 1) * 16384 + dst);
          async_cp16(Vb + kn + voff[i], (char*)Vs + (cur ^ 1) * 16384 + dst);
        }
      }

      const bf16* Kcur = &Ks[cur][0][0];
      const bf16* Vcur = &Vs[cur][0][0];

      // S^T tiles: s4t[j] = K_tile_j x Q^T ; C: col=l15=qrow, row=quad*4+r=key
      f32x4 s4t[4];
#pragma unroll
      for (int j = 0; j < 4; j++) {
        f32x4 acc = (f32x4)0.0f;
        const int krow = j * 16 + l15;
#pragma unroll
        for (int kk = 0; kk < 4; kk++) {
          bf16x8 bk = *(const bf16x8*)(Kcur + krow * 128 + (((kk * 4 + quad) ^ l15) * 8));
          acc = __builtin_amdgcn_mfma_f32_16x16x32_bf16(bk, aq[kk], acc, 0, 0, 0);
        }
        s4t[j] = acc;
      }

      // fixed-max softmax + pack to bf16 pairs (registers only)
      const bool diag = (kt == qb);
      unsigned pp[4][2];
#pragma unroll
      for (int j = 0; j < 4; j++) {
        const int kbase = k0 + j * 16 + quad * 4;
        float pv[4];
#pragma unroll
        for (int r = 0; r < 4; r++) {
          float e = EXP2F(s4t[j][r] * cexp);
          if (diag && (kbase + r > qrow)) e = 0.0f;
          pv[r] = e;
        }
        union { bf16x2 h; unsigned u; } u0, u1;
        u0.h[0] = (bf16)pv[0]; u0.h[1] = (bf16)pv[1];
        u1.h[0] = (bf16)pv[2]; u1.h[1] = (bf16)pv[3];
        pp[j][0] = u0.u; pp[j][1] = u1.u;
      }

      // P^T -> PV B-operand via register shuffles; O^T += V^T P^T
#pragma unroll
      for (int kk = 0; kk < 2; kk++) {
        const int ja = 2 * kk, jb = 2 * kk + 1;
        unsigned a00 = (unsigned)__shfl((int)pp[ja][0], srcA, 64);
        unsigned a01 = (unsigned)__shfl((int)pp[ja][1], srcA, 64);
        unsigned a10 = (unsigned)__shfl((int)pp[jb][0], srcA, 64);
        unsigned a11 = (unsigned)__shfl((int)pp[jb][1], srcA, 64);
        unsigned b00 = (unsigned)__shfl((int)pp[ja][0], srcB, 64);
        unsigned b01 = (unsigned)__shfl((int)pp[ja][1], srcB, 64);
        unsigned b10 = (unsigned)__shfl((int)pp[jb][0], srcB, 64);
        unsigned b11 = (unsigned)__shfl((int)pp[jb][1], srcB, 64);
        union { unsigned u[4]; bf16x8 v; } ub;
        ub.u[0] = hiSel ? a10 : a00;
        ub.u[1] = hiSel ? a11 : a01;
        ub.u[2] = hiSel ? b10 : b00;
        ub.u[3] = hiSel ? b11 : b01;
#pragma unroll
        for (int dt = 0; dt < 8; dt++) {
          const int d = dt * 16 + l15;
          bf16x8 av = *(const bf16x8*)(Vcur + d * 64 + (((kk * 4 + quad) ^ (d & 7)) * 8));
          o[dt] = __builtin_amdgcn_mfma_f32_16x16x32_bf16(av, ub.v, o[dt], 0, 0, 0);
        }
        o8 = __builtin_amdgcn_mfma_f32_16x16x32_bf16(onesA, ub.v, o8, 0, 0, 0);
      }
    }

    // epilogue: O^T C-layout: col=l15=qrow, row=quad*4+r = d within tile dt
    const float rinv = 1.0f / o8[0];
    bf16* Ob = O + ((size_t)(b * 2048) + qrow) * 2048 + h * 128;
#pragma unroll
    for (int dt = 0; dt < 8; dt++) {
      bf16x4 pk;
#pragma unroll
      for (int r = 0; r < 4; r++) pk[r] = (bf16)(o[dt][r] * rinv);
      *(bf16x4*)(Ob + dt * 16 + quad * 4) = pk;
    }
  }
}

// ============================================================
// Launcher — fp32 in/out, bf16 compute. 5 kernel launches.
// ws layout (bytes), total 88080384:
//   xb    bf16[4096x2048] : 0        .. 16777216  (reused as At)
//   wqkvb bf16[3072x2048] : 16777216 .. 29360128
//   wob   bf16[2048x2048] : 29360128 .. 37748736
//   qkvb  bf16[4096x3072] : 37748736 .. 62914560
//   Qr    bf16[2,16,2048,128] : 62914560 .. 79691776
//   Kr    bf16[2, 4,2048,128] : 79691776 .. 83886080
//   Vt    bf16[2, 4,128,2048] : 83886080 .. 88080384
// ============================================================
extern "C" void kernel_launch(void* const* d_in, const int* in_sizes, int n_in,
                              void* d_out, int out_size, void* d_ws, size_t ws_size,
                              hipStream_t stream) {
  const float* x   = (const float*)d_in[0];
  const float* wq  = (const float*)d_in[1];
  const float* bq  = (const float*)d_in[2];
  const float* wk  = (const float*)d_in[3];
  const float* bk  = (const float*)d_in[4];
  const float* wv  = (const float*)d_in[5];
  const float* bv  = (const float*)d_in[6];
  const float* wo  = (const float*)d_in[7];
  const float* bo  = (const float*)d_in[8];
  const float* qg  = (const float*)d_in[9];
  const float* qbt = (const float*)d_in[10];
  const float* kg  = (const float*)d_in[11];
  const float* kbt = (const float*)d_in[12];
  float* out = (float*)d_out;

  char* ws = (char*)d_ws;
  if (ws_size < (size_t)88080384) return;
  bf16* xb    = (bf16*)(ws);
  bf16* wqkvb = (bf16*)(ws + 16777216);
  bf16* wob   = (bf16*)(ws + 29360128);
  bf16* qkvb  = (bf16*)(ws + 37748736);
  bf16* Qr    = (bf16*)(ws + 62914560);
  bf16* Kr    = (bf16*)(ws + 79691776);
  bf16* Vt    = (bf16*)(ws + 83886080);
  bf16* At    = (bf16*)(ws);  // aliases xb — x dead after QKV gemm

  cast_all<<<9216, 256, 0, stream>>>(x, wq, wk, wv, wo, xb, wqkvb, wob);
  gemm_bt<bf16, true, true><<<dim3(32, 24), 256, 0, stream>>>(
      xb, wqkvb, bq, bk, bv, qkvb, 4096, 3072, 2048);
  fused_mid<<<8448, 256, 0, stream>>>(qkvb, qg, qbt, kg, kbt, Qr, Kr, Vt);
  flash_attn<<<dim3(16, 8, 2), 512, 0, stream>>>(Qr, Kr, Vt, At);
  gemm_bt<float, false, false><<<dim3(32, 16), 256, 0, stream>>>(
      At, wob, bo, nullptr, nullptr, out, 4096, 2048, 2048);
}